// Round 10
// baseline (107.741 us; speedup 1.0000x reference)
//
#include <hip/hip_runtime.h>
#include <math.h>

#define Bn 2048
#define Dd 128
#define Cc 50000
#define NSPL 32
#define NT128 391   // ceil(50000/128) tiles of 128 cols
#define TS 32       // triplet col-splits (64 cols each)

#define COS_Mf 0.8775825618903728f
#define SIN_Mf 0.479425538604203f
#define THf (-0.8775825618903728f)
#define MMf 0.2397127693021015f
#define L2E64 92.33248261689366f   // 64 * log2(e)

typedef __attribute__((ext_vector_type(8))) short short8;
typedef __attribute__((ext_vector_type(4))) float f32x4;

__device__ __forceinline__ unsigned short f2bf(float f) {
    unsigned int u = __float_as_uint(f);
    u += 0x7fffu + ((u >> 16) & 1u);
    return (unsigned short)(u >> 16);
}
__device__ __forceinline__ float bf2f(unsigned short h) {
    return __uint_as_float(((unsigned int)h) << 16);
}

// ---------------- row normalization -> bf16, float4-vectorized (8 rows/block) ----------------
__global__ void norm_all(const float* __restrict__ emb, const float* __restrict__ W,
                         unsigned short* __restrict__ embn, unsigned short* __restrict__ rawb,
                         float* __restrict__ sqn, unsigned short* __restrict__ wnb,
                         float* __restrict__ zp) {
    if (blockIdx.x == 0) zp[threadIdx.x] = 0.f;    // esum|wsum (256 floats)
    int wid = threadIdx.x >> 6;
    int lane = threadIdx.x & 63;
    int half = lane >> 5, l32 = lane & 31;
    int row = blockIdx.x * 8 + wid * 2 + half;
    bool ise = row < Bn;
    int r = ise ? row : row - Bn;
    const float* p = (ise ? emb : W) + (size_t)r * Dd + l32 * 4;
    float4 v = *reinterpret_cast<const float4*>(p);
    float ss = v.x * v.x + v.y * v.y + v.z * v.z + v.w * v.w;
    #pragma unroll
    for (int o = 16; o > 0; o >>= 1) ss += __shfl_xor(ss, o);   // stays within 32-lane half
    float rn = rsqrtf(ss);
    ushort4 q4 = make_ushort4(f2bf(v.x * rn), f2bf(v.y * rn), f2bf(v.z * rn), f2bf(v.w * rn));
    *reinterpret_cast<ushort4*>((ise ? embn : wnb) + (size_t)r * Dd + l32 * 4) = q4;
    if (ise) {
        ushort4 r4 = make_ushort4(f2bf(v.x), f2bf(v.y), f2bf(v.z), f2bf(v.w));
        *reinterpret_cast<ushort4*>(rawb + (size_t)r * Dd + l32 * 4) = r4;
        if (l32 == 0) sqn[r] = ss;
    }
}

// ---------------- column sums (blocks 0..271) + per-row label logits (blocks 272..783) ----------------
__global__ void aux_k(const unsigned short* __restrict__ embn,
                      const unsigned short* __restrict__ wnb,
                      const int* __restrict__ lab,
                      float* __restrict__ esum, float* __restrict__ wsum,
                      float* __restrict__ bx, float* __restrict__ tg) {
    __shared__ float s[16][128];
    int t = threadIdx.x;
    if (blockIdx.x < 272) {
        int rg = t >> 4;
        int cg = (t & 15) * 8;
        const unsigned short* src;
        float* dst;
        int r0, rend;
        if (blockIdx.x < 256) {
            src = wnb; dst = wsum;
            r0 = blockIdx.x * 196;
            rend = r0 + 196; if (rend > Cc) rend = Cc;
        } else {
            src = embn; dst = esum;
            r0 = (blockIdx.x - 256) * 128;
            rend = r0 + 128;
        }
        float acc[8];
        #pragma unroll
        for (int j = 0; j < 8; ++j) acc[j] = 0.f;
        for (int r = r0 + rg; r < rend; r += 16) {
            short8 v = *reinterpret_cast<const short8*>(src + (size_t)r * Dd + cg);
            #pragma unroll
            for (int j = 0; j < 8; ++j) acc[j] += bf2f((unsigned short)v[j]);
        }
        #pragma unroll
        for (int j = 0; j < 8; ++j) s[rg][cg + j] = acc[j];
        __syncthreads();
        if (t < 128) {
            float v = 0.f;
            #pragma unroll
            for (int u = 0; u < 16; ++u) v += s[u][t];
            atomicAdd(&dst[t], v);
        }
    } else {
        int wid = t >> 6, lane = t & 63;
        int row = (blockIdx.x - 272) * 4 + wid;
        int lb = lab[row];
        const unsigned short* e = embn + (size_t)row * Dd;
        const unsigned short* wv = wnb + (size_t)lb * Dd;
        float sv = bf2f(e[lane]) * bf2f(wv[lane]) + bf2f(e[lane + 64]) * bf2f(wv[lane + 64]);
        #pragma unroll
        for (int o = 32; o > 0; o >>= 1) sv += __shfl_xor(sv, o);
        if (lane == 0) {
            float c = sv;
            float s2 = fminf(fmaxf(1.f - c * c, 0.f), 1.f);
            float sine = sqrtf(s2);
            float phi = c * COS_Mf - sine * SIN_Mf;
            phi = (c > THf) ? phi : (c - MMf);
            bx[row] = 64.f * c;
            tg[row] = 64.f * phi;
        }
    }
}

// ---------------- fused bf16-MFMA cosine-GEMM + fixed-max softmax partials ----------------
// grid dim3(16, NSPL); 512 threads = 8 waves. 128 cols staged per phase (2 x 64-col
// subtiles computed per barrier pair) to amortize the stage+drain+barrier overhead.
// Wave tile per subtile: 64 rows x 16 cols (4 sm x 1 col-group).
__launch_bounds__(512, 4)
__global__ void arc_main(const unsigned short* __restrict__ en,
                         const unsigned short* __restrict__ wn,
                         float* __restrict__ ps) {
    __shared__ unsigned short swb[2][16384];  // 2 x 32KB: [col 0..127][k 0..127], XOR-swizzled
    __shared__ float sred[8][64];
    const int t = threadIdx.x;
    const int w = t >> 6, l = t & 63;
    const int r0 = blockIdx.x * 128;
    const int split = blockIdx.y;
    const int rowbase = r0 + (w & 1) * 64;
    const int cg16 = (w >> 1) * 16;           // col-group within each 64-col subtile

    short8 afrag[4][4];
    #pragma unroll
    for (int sm = 0; sm < 4; ++sm) {
        #pragma unroll
        for (int kc = 0; kc < 4; ++kc) {
            int row = rowbase + sm * 16 + (l & 15);
            int k0 = kc * 32 + (l >> 4) * 8;
            afrag[sm][kc] = *reinterpret_cast<const short8*>(en + (size_t)row * Dd + k0);
        }
    }

    float sacc[4][4];
    #pragma unroll
    for (int sm = 0; sm < 4; ++sm)
        #pragma unroll
        for (int r = 0; r < 4; ++r) sacc[sm][r] = 0.f;

    const int ntm = (NT128 - 1 - split) / NSPL + 1;

    auto STAGE = [&](int buf, int idx) {
        int tl = split + idx * NSPL;
        if (tl > NT128 - 1) tl = NT128 - 1;
        int c0t = tl * 128;
        #pragma unroll
        for (int j = 0; j < 4; ++j) {
            int g = w * 4 + j;                   // col-group 0..31 (4 cols each)
            int col = g * 4 + (l >> 4);          // 0..127
            int kb = ((l & 15) * 16) ^ ((col & 7) << 4);
            int c = c0t + col;
            if (c > Cc - 1) c = Cc - 1;
            const unsigned short* src = wn + ((size_t)c << 7) + (kb >> 1);
            __builtin_amdgcn_global_load_lds(
                (const __attribute__((address_space(1))) void*)src,
                (__attribute__((address_space(3))) void*)(&swb[buf][g * 512]),
                16, 0, 0);
        }
    };

    STAGE(0, 0);
    for (int i = 0; i < ntm; ++i) {
        __syncthreads();
        STAGE((i & 1) ^ 1, i + 1);
        const unsigned short* bb = swb[i & 1];
        const int c0t = (split + i * NSPL) * 128;

        #pragma unroll
        for (int st = 0; st < 2; ++st) {
            const unsigned short* bsub = bb + st * 8192;   // 64 cols x 128 k
            const int rcol = cg16 + (l & 15);              // 0..63 within subtile (col&7 preserved)

            f32x4 acc[4];
            #pragma unroll
            for (int sm = 0; sm < 4; ++sm) acc[sm] = (f32x4){0.f, 0.f, 0.f, 0.f};

            #pragma unroll
            for (int kc = 0; kc < 4; ++kc) {
                int rkb = (kc * 64 + (l >> 4) * 16) ^ ((rcol & 7) << 4);
                short8 bfr = *reinterpret_cast<const short8*>(bsub + rcol * 128 + (rkb >> 1));
                #pragma unroll
                for (int sm = 0; sm < 4; ++sm)
                    acc[sm] = __builtin_amdgcn_mfma_f32_16x16x32_bf16(
                        afrag[sm][kc], bfr, acc[sm], 0, 0, 0);
            }

            if (c0t + st * 64 + cg16 < Cc) {   // 16-col granularity; 50000 % 16 == 0
                #pragma unroll
                for (int sm = 0; sm < 4; ++sm)
                    #pragma unroll
                    for (int r = 0; r < 4; ++r)
                        sacc[sm][r] += __builtin_amdgcn_exp2f(
                            fmaf(acc[sm][r], L2E64, -L2E64));
            }
        }
    }

    // reduce over the wave's 16 col-lanes; C/D layout: col=l&15, row=(l>>4)*4+r
    #pragma unroll
    for (int sm = 0; sm < 4; ++sm)
        #pragma unroll
        for (int r = 0; r < 4; ++r) {
            float v = sacc[sm][r];
            v += __shfl_xor(v, 1); v += __shfl_xor(v, 2);
            v += __shfl_xor(v, 4); v += __shfl_xor(v, 8);
            sacc[sm][r] = v;
        }

    if ((l & 15) == 0) {
        #pragma unroll
        for (int sm = 0; sm < 4; ++sm)
            #pragma unroll
            for (int r = 0; r < 4; ++r)
                sred[w][sm * 16 + (l >> 4) * 4 + r] = sacc[sm][r];
    }
    __syncthreads();
    if (t < 128) {
        int h = t >> 6, idx = t & 63;
        float sv = sred[h][idx] + sred[2 + h][idx] + sred[4 + h][idx] + sred[6 + h][idx];
        ps[(size_t)split * Bn + r0 + t] = sv;
    }
}

// ---------------- batch-hard triplet: bf16 MFMA self-GEMM + masked max/min ----------------
// (R9-proven version, verbatim)
__launch_bounds__(256, 2)
__global__ void trip_k(const unsigned short* __restrict__ eb, const float* __restrict__ sqn,
                       const int* __restrict__ lab,
                       float* __restrict__ hp, float* __restrict__ hn,
                       float* __restrict__ cnt) {
    __shared__ unsigned short swt[8192];      // 16KB: one 64-col tile, XOR-swizzled
    __shared__ float red[128][2][3];
    const int t = threadIdx.x;
    const int w = t >> 6, l = t & 63;
    const int r0 = blockIdx.x * 128;
    const int split = blockIdx.y;
    const int c0 = split * 64;
    const int rowbase = r0 + (w & 1) * 64;
    const int colb = (w >> 1) * 32;

    #pragma unroll
    for (int j = 0; j < 4; ++j) {
        int col = (w * 4 + j) * 4 + (l >> 4);
        int kb = ((l & 15) * 16) ^ ((col & 7) << 4);
        const unsigned short* src = eb + ((size_t)(c0 + col) << 7) + (kb >> 1);
        __builtin_amdgcn_global_load_lds(
            (const __attribute__((address_space(1))) void*)src,
            (__attribute__((address_space(3))) void*)(&swt[(w * 4 + j) * 512]),
            16, 0, 0);
    }

    short8 afrag[4][4];
    #pragma unroll
    for (int sm = 0; sm < 4; ++sm)
        #pragma unroll
        for (int kc = 0; kc < 4; ++kc) {
            int row = rowbase + sm * 16 + (l & 15);
            int k0 = kc * 32 + (l >> 4) * 8;
            afrag[sm][kc] = *reinterpret_cast<const short8*>(eb + (size_t)row * Dd + k0);
        }

    float rsq[4][4]; int rlb[4][4];
    #pragma unroll
    for (int sm = 0; sm < 4; ++sm)
        #pragma unroll
        for (int r = 0; r < 4; ++r) {
            int row = rowbase + sm * 16 + (l >> 4) * 4 + r;
            rsq[sm][r] = sqn[row];
            rlb[sm][r] = lab[row];
        }
    int cj[2]; float csq[2]; int clb[2];
    #pragma unroll
    for (int sn = 0; sn < 2; ++sn) {
        cj[sn] = c0 + colb + sn * 16 + (l & 15);
        csq[sn] = sqn[cj[sn]];
        clb[sn] = lab[cj[sn]];
    }

    __syncthreads();

    f32x4 acc[4][2];
    #pragma unroll
    for (int sm = 0; sm < 4; ++sm)
        #pragma unroll
        for (int sn = 0; sn < 2; ++sn)
            acc[sm][sn] = (f32x4){0.f, 0.f, 0.f, 0.f};

    #pragma unroll
    for (int kc = 0; kc < 4; ++kc) {
        short8 bfr[2];
        #pragma unroll
        for (int sn = 0; sn < 2; ++sn) {
            int rcol = colb + sn * 16 + (l & 15);
            int rkb = (kc * 64 + (l >> 4) * 16) ^ ((rcol & 7) << 4);
            bfr[sn] = *reinterpret_cast<const short8*>(swt + rcol * 128 + (rkb >> 1));
        }
        #pragma unroll
        for (int sn = 0; sn < 2; ++sn)
            #pragma unroll
            for (int sm = 0; sm < 4; ++sm)
                acc[sm][sn] = __builtin_amdgcn_mfma_f32_16x16x32_bf16(
                    afrag[sm][kc], bfr[sn], acc[sm][sn], 0, 0, 0);
    }

    float vhp[4][4], vhn[4][4], vct[4][4];
    #pragma unroll
    for (int sm = 0; sm < 4; ++sm)
        #pragma unroll
        for (int r = 0; r < 4; ++r) { vhp[sm][r] = 0.f; vhn[sm][r] = 1e30f; vct[sm][r] = 0.f; }

    #pragma unroll
    for (int sm = 0; sm < 4; ++sm)
        #pragma unroll
        for (int r = 0; r < 4; ++r) {
            int rg = rowbase + sm * 16 + (l >> 4) * 4 + r;
            #pragma unroll
            for (int sn = 0; sn < 2; ++sn) {
                float d2 = fmaf(acc[sm][sn][r], -2.f, rsq[sm][r] + csq[sn]);
                float dist = sqrtf(fmaxf(d2, 0.f) + 1e-16f);
                bool same = (rlb[sm][r] == clb[sn]);
                bool psel = same && (rg != cj[sn]);
                if (psel) { vhp[sm][r] = fmaxf(vhp[sm][r], dist); vct[sm][r] += 1.f; }
                if (!same) vhn[sm][r] = fminf(vhn[sm][r], dist);
            }
        }

    #pragma unroll
    for (int sm = 0; sm < 4; ++sm)
        #pragma unroll
        for (int r = 0; r < 4; ++r) {
            float a = vhp[sm][r], b = vhn[sm][r], c = vct[sm][r];
            #pragma unroll
            for (int o = 1; o < 16; o <<= 1) {
                a = fmaxf(a, __shfl_xor(a, o));
                b = fminf(b, __shfl_xor(b, o));
                c += __shfl_xor(c, o);
            }
            if ((l & 15) == 0) {
                int row = (w & 1) * 64 + sm * 16 + (l >> 4) * 4 + r;
                red[row][w >> 1][0] = a;
                red[row][w >> 1][1] = b;
                red[row][w >> 1][2] = c;
            }
        }
    __syncthreads();
    if (t < 128) {
        float a = fmaxf(red[t][0][0], red[t][1][0]);
        float b = fminf(red[t][0][1], red[t][1][1]);
        float c = red[t][0][2] + red[t][1][2];
        hp[(size_t)split * Bn + r0 + t] = a;
        hn[(size_t)split * Bn + r0 + t] = b;
        cnt[(size_t)split * Bn + r0 + t] = c;
    }
}

// ---------------- per-row merge -> per-block partials (no atomics) ----------------
__launch_bounds__(256)
__global__ void final_k(const float* __restrict__ ps, const float* __restrict__ bx,
                        const float* __restrict__ tg, const float* __restrict__ hp,
                        const float* __restrict__ hn, const float* __restrict__ cnt,
                        float* __restrict__ gpart) {
    __shared__ float sA[4], sT[4], sV[4];
    int row = blockIdx.x * 256 + threadIdx.x;
    float s = 0.f;
    for (int u = 0; u < NSPL; ++u) s += ps[(size_t)u * Bn + row];
    float base = bx[row], targ = tg[row];
    s += __expf(targ - 64.f) - __expf(base - 64.f);
    float lse = 64.f + logf(s);
    float arcs = lse - 0.9f * targ - 0.1f * (targ - base) / (float)Cc;

    float a = 0.f, b = 1e30f, c = 0.f;
    for (int u = 0; u < TS; ++u) {
        a = fmaxf(a, hp[(size_t)u * Bn + row]);
        b = fminf(b, hn[(size_t)u * Bn + row]);
        c += cnt[(size_t)u * Bn + row];
    }
    float tl = fmaxf(a - b + 0.3f, 0.f);
    float tris = (c > 0.f) ? tl : 0.f;
    float vals = (c > 0.f) ? 1.f : 0.f;

    #pragma unroll
    for (int o = 32; o > 0; o >>= 1) {
        arcs += __shfl_xor(arcs, o);
        tris += __shfl_xor(tris, o);
        vals += __shfl_xor(vals, o);
    }
    int wid = threadIdx.x >> 6, lane = threadIdx.x & 63;
    if (lane == 0) { sA[wid] = arcs; sT[wid] = tris; sV[wid] = vals; }
    __syncthreads();
    if (threadIdx.x == 0) {
        gpart[blockIdx.x * 3 + 0] = sA[0] + sA[1] + sA[2] + sA[3];
        gpart[blockIdx.x * 3 + 1] = sT[0] + sT[1] + sT[2] + sT[3];
        gpart[blockIdx.x * 3 + 2] = sV[0] + sV[1] + sV[2] + sV[3];
    }
}

// ---------------- scalar finish ----------------
__global__ void final2_k(const float* __restrict__ gpart, const float* __restrict__ es,
                         const float* __restrict__ wsum, float* __restrict__ out) {
    int l = threadIdx.x;   // 64
    float x = es[l] * wsum[l] + es[l + 64] * wsum[l + 64];
    #pragma unroll
    for (int o = 32; o > 0; o >>= 1) x += __shfl_xor(x, o);
    if (l == 0) {
        float A = 0.f, T = 0.f, V = 0.f;
        for (int b = 0; b < Bn / 256; ++b) {
            A += gpart[b * 3 + 0];
            T += gpart[b * 3 + 1];
            V += gpart[b * 3 + 2];
        }
        float tri = (V > 0.f) ? (T / fmaxf(V, 1.f)) : 0.f;
        out[0] = (A - 6.4f * x / (float)Cc) / (float)Bn + 0.5f * tri;
    }
}

extern "C" void kernel_launch(void* const* d_in, const int* in_sizes, int n_in,
                              void* d_out, int out_size, void* d_ws, size_t ws_size,
                              hipStream_t stream) {
    const float* emb = (const float*)d_in[0];
    const float* W = (const float*)d_in[1];
    const int* lab = (const int*)d_in[2];
    float* out = (float*)d_out;

    unsigned short* embn = (unsigned short*)d_ws;          // 2048*128 bf16
    unsigned short* rawb = embn + (size_t)Bn * Dd;         // 2048*128 bf16
    unsigned short* wnb = rawb + (size_t)Bn * Dd;          // 50000*128 bf16
    float* sqn = (float*)(wnb + (size_t)Cc * Dd);          // 2048
    float* ps = sqn + Bn;                                  // NSPL*2048
    float* bx = ps + (size_t)NSPL * Bn;                    // 2048
    float* tg = bx + Bn;                                   // 2048
    float* hp = tg + Bn;                                   // TS*2048
    float* hn = hp + (size_t)TS * Bn;                      // TS*2048
    float* ct = hn + (size_t)TS * Bn;                      // TS*2048
    float* esum = ct + (size_t)TS * Bn;                    // 128
    float* wsum = esum + 128;                              // 128
    float* gpart = wsum + 128;                             // 24

    norm_all<<<256 + Cc / 8, 256, 0, stream>>>(emb, W, embn, rawb, sqn, wnb, esum);
    aux_k<<<272 + Bn / 4, 256, 0, stream>>>(embn, wnb, lab, esum, wsum, bx, tg);
    arc_main<<<dim3(16, NSPL), 512, 0, stream>>>(embn, wnb, ps);
    trip_k<<<dim3(16, TS), 256, 0, stream>>>(rawb, sqn, lab, hp, hn, ct);
    final_k<<<Bn / 256, 256, 0, stream>>>(ps, bx, tg, hp, hn, ct, gpart);
    final2_k<<<1, 64, 0, stream>>>(gpart, esum, wsum, out);
}

// Round 11
// 97.864 us; speedup vs baseline: 1.1009x; 1.1009x over previous
//
#include <hip/hip_runtime.h>
#include <math.h>

#define Bn 2048
#define Dd 128
#define Cc 50000
#define ASPL 128    // arc col-splits (16-col chunks, strided)
#define TS 32       // triplet col-splits (64 cols each)

#define COS_Mf 0.8775825618903728f
#define SIN_Mf 0.479425538604203f
#define THf (-0.8775825618903728f)
#define MMf 0.2397127693021015f
#define L2E64 92.33248261689366f   // 64 * log2(e)

typedef __attribute__((ext_vector_type(8))) short short8;
typedef __attribute__((ext_vector_type(4))) float f32x4;

__device__ __forceinline__ unsigned short f2bf(float f) {
    unsigned int u = __float_as_uint(f);
    u += 0x7fffu + ((u >> 16) & 1u);
    return (unsigned short)(u >> 16);
}
__device__ __forceinline__ float bf2f(unsigned short h) {
    return __uint_as_float(((unsigned int)h) << 16);
}

// ---------------- row normalization -> bf16, float4-vectorized (8 rows/block) ----------------
__global__ void norm_all(const float* __restrict__ emb, const float* __restrict__ W,
                         unsigned short* __restrict__ embn, unsigned short* __restrict__ rawb,
                         float* __restrict__ sqn, unsigned short* __restrict__ wnb,
                         float* __restrict__ zp) {
    if (blockIdx.x == 0) zp[threadIdx.x] = 0.f;    // esum|wsum (256 floats)
    int wid = threadIdx.x >> 6;
    int lane = threadIdx.x & 63;
    int half = lane >> 5, l32 = lane & 31;
    int row = blockIdx.x * 8 + wid * 2 + half;
    bool ise = row < Bn;
    int r = ise ? row : row - Bn;
    const float* p = (ise ? emb : W) + (size_t)r * Dd + l32 * 4;
    float4 v = *reinterpret_cast<const float4*>(p);
    float ss = v.x * v.x + v.y * v.y + v.z * v.z + v.w * v.w;
    #pragma unroll
    for (int o = 16; o > 0; o >>= 1) ss += __shfl_xor(ss, o);   // stays within 32-lane half
    float rn = rsqrtf(ss);
    ushort4 q4 = make_ushort4(f2bf(v.x * rn), f2bf(v.y * rn), f2bf(v.z * rn), f2bf(v.w * rn));
    *reinterpret_cast<ushort4*>((ise ? embn : wnb) + (size_t)r * Dd + l32 * 4) = q4;
    if (ise) {
        ushort4 r4 = make_ushort4(f2bf(v.x), f2bf(v.y), f2bf(v.z), f2bf(v.w));
        *reinterpret_cast<ushort4*>(rawb + (size_t)r * Dd + l32 * 4) = r4;
        if (l32 == 0) sqn[r] = ss;
    }
}

// ---------------- column sums (blocks 0..271) + per-row label logits (blocks 272..783) ----------------
__global__ void aux_k(const unsigned short* __restrict__ embn,
                      const unsigned short* __restrict__ wnb,
                      const int* __restrict__ lab,
                      float* __restrict__ esum, float* __restrict__ wsum,
                      float* __restrict__ bx, float* __restrict__ tg) {
    __shared__ float s[16][128];
    int t = threadIdx.x;
    if (blockIdx.x < 272) {
        int rg = t >> 4;
        int cg = (t & 15) * 8;
        const unsigned short* src;
        float* dst;
        int r0, rend;
        if (blockIdx.x < 256) {
            src = wnb; dst = wsum;
            r0 = blockIdx.x * 196;
            rend = r0 + 196; if (rend > Cc) rend = Cc;
        } else {
            src = embn; dst = esum;
            r0 = (blockIdx.x - 256) * 128;
            rend = r0 + 128;
        }
        float acc[8];
        #pragma unroll
        for (int j = 0; j < 8; ++j) acc[j] = 0.f;
        for (int r = r0 + rg; r < rend; r += 16) {
            short8 v = *reinterpret_cast<const short8*>(src + (size_t)r * Dd + cg);
            #pragma unroll
            for (int j = 0; j < 8; ++j) acc[j] += bf2f((unsigned short)v[j]);
        }
        #pragma unroll
        for (int j = 0; j < 8; ++j) s[rg][cg + j] = acc[j];
        __syncthreads();
        if (t < 128) {
            float v = 0.f;
            #pragma unroll
            for (int u = 0; u < 16; ++u) v += s[u][t];
            atomicAdd(&dst[t], v);
        }
    } else {
        int wid = t >> 6, lane = t & 63;
        int row = (blockIdx.x - 272) * 4 + wid;
        int lb = lab[row];
        const unsigned short* e = embn + (size_t)row * Dd;
        const unsigned short* wv = wnb + (size_t)lb * Dd;
        float sv = bf2f(e[lane]) * bf2f(wv[lane]) + bf2f(e[lane + 64]) * bf2f(wv[lane + 64]);
        #pragma unroll
        for (int o = 32; o > 0; o >>= 1) sv += __shfl_xor(sv, o);
        if (lane == 0) {
            float c = sv;
            float s2 = fminf(fmaxf(1.f - c * c, 0.f), 1.f);
            float sine = sqrtf(s2);
            float phi = c * COS_Mf - sine * SIN_Mf;
            phi = (c > THf) ? phi : (c - MMf);
            bx[row] = 64.f * c;
            tg[row] = 64.f * phi;
        }
    }
}

// ---------------- fused bf16-MFMA cosine-GEMM + fixed-max softmax partials ----------------
// Barrier-free, LDS-free. 2048 independent waves = 16 row-groups x 128 col-splits.
// Wave: A panel 128 rows x 128 k in VGPRs; B 16-col chunk loaded straight to regs
// (frag layout col=l&15, k=(l>>4)*8+kc*32), double-buffered, prefetch 1 chunk ahead.
// The 4 waves of a block share the same split -> same B addresses -> L1 reuse.
#define LOADB(B, p) {                                        \
    B[0] = *reinterpret_cast<const short8*>(p);              \
    B[1] = *reinterpret_cast<const short8*>((p) + 32);       \
    B[2] = *reinterpret_cast<const short8*>((p) + 64);       \
    B[3] = *reinterpret_cast<const short8*>((p) + 96); }

#define COMPUTE(B) {                                                          \
    f32x4 acc_[8];                                                            \
    _Pragma("unroll")                                                         \
    for (int sm_ = 0; sm_ < 8; ++sm_) acc_[sm_] = (f32x4){0.f, 0.f, 0.f, 0.f};\
    _Pragma("unroll")                                                         \
    for (int kc_ = 0; kc_ < 4; ++kc_) {                                       \
        _Pragma("unroll")                                                     \
        for (int sm_ = 0; sm_ < 8; ++sm_)                                     \
            acc_[sm_] = __builtin_amdgcn_mfma_f32_16x16x32_bf16(              \
                afrag[sm_][kc_], B[kc_], acc_[sm_], 0, 0, 0);                 \
    }                                                                         \
    _Pragma("unroll")                                                         \
    for (int sm_ = 0; sm_ < 8; ++sm_)                                         \
        _Pragma("unroll")                                                     \
        for (int r_ = 0; r_ < 4; ++r_)                                        \
            sacc[sm_][r_] += __builtin_amdgcn_exp2f(                          \
                fmaf(acc_[sm_][r_], L2E64, -L2E64)); }

__launch_bounds__(256, 2)
__global__ void arc_main(const unsigned short* __restrict__ en,
                         const unsigned short* __restrict__ wn,
                         float* __restrict__ ps) {
    const int t = threadIdx.x;
    const int w = t >> 6, l = t & 63;
    const int wid = blockIdx.x * 4 + w;
    const int split = wid >> 4;      // 0..127 (shared by the block's 4 waves)
    const int rg = wid & 15;         // 0..15
    const int lc = l & 15, lk = l >> 4;

    // A panel: 128 rows x 128 k
    short8 afrag[8][4];
    #pragma unroll
    for (int sm = 0; sm < 8; ++sm)
        #pragma unroll
        for (int kc = 0; kc < 4; ++kc)
            afrag[sm][kc] = *reinterpret_cast<const short8*>(
                en + (size_t)(rg * 128 + sm * 16 + lc) * Dd + kc * 32 + lk * 8);

    float sacc[8][4];
    #pragma unroll
    for (int sm = 0; sm < 8; ++sm)
        #pragma unroll
        for (int r = 0; r < 4; ++r) sacc[sm][r] = 0.f;

    const int nch = (3125 - split + 127) / 128;    // 24 or 25 chunks of 16 cols
    const unsigned short* p = wn + ((size_t)(split * 16 + lc) << 7) + lk * 8;
    const size_t CSTEP = (size_t)128 * 2048;       // 128 chunks x 16 cols x 128 el

    short8 bA[4], bB[4];
    LOADB(bA, p);
    for (int i = 0; i + 1 < nch; ++i) {
        const unsigned short* pn = p + CSTEP;
        if (i & 1) { LOADB(bA, pn); COMPUTE(bB); }
        else       { LOADB(bB, pn); COMPUTE(bA); }
        p = pn;
    }
    if ((nch - 1) & 1) { COMPUTE(bB); } else { COMPUTE(bA); }

    // reduce over the wave's 16 col-lanes; C/D layout: col=l&15, row=(l>>4)*4+r
    #pragma unroll
    for (int sm = 0; sm < 8; ++sm)
        #pragma unroll
        for (int r = 0; r < 4; ++r) {
            float v = sacc[sm][r];
            v += __shfl_xor(v, 1); v += __shfl_xor(v, 2);
            v += __shfl_xor(v, 4); v += __shfl_xor(v, 8);
            sacc[sm][r] = v;
        }
    if (lc == 0) {
        #pragma unroll
        for (int sm = 0; sm < 8; ++sm)
            #pragma unroll
            for (int r = 0; r < 4; ++r)
                ps[(size_t)split * Bn + rg * 128 + sm * 16 + lk * 4 + r] = sacc[sm][r];
    }
}

// ---------------- batch-hard triplet: bf16 MFMA self-GEMM + masked max/min ----------------
// (R9-proven version, verbatim)
__launch_bounds__(256, 2)
__global__ void trip_k(const unsigned short* __restrict__ eb, const float* __restrict__ sqn,
                       const int* __restrict__ lab,
                       float* __restrict__ hp, float* __restrict__ hn,
                       float* __restrict__ cnt) {
    __shared__ unsigned short swt[8192];      // 16KB: one 64-col tile, XOR-swizzled
    __shared__ float red[128][2][3];
    const int t = threadIdx.x;
    const int w = t >> 6, l = t & 63;
    const int r0 = blockIdx.x * 128;
    const int split = blockIdx.y;
    const int c0 = split * 64;
    const int rowbase = r0 + (w & 1) * 64;
    const int colb = (w >> 1) * 32;

    #pragma unroll
    for (int j = 0; j < 4; ++j) {
        int col = (w * 4 + j) * 4 + (l >> 4);
        int kb = ((l & 15) * 16) ^ ((col & 7) << 4);
        const unsigned short* src = eb + ((size_t)(c0 + col) << 7) + (kb >> 1);
        __builtin_amdgcn_global_load_lds(
            (const __attribute__((address_space(1))) void*)src,
            (__attribute__((address_space(3))) void*)(&swt[(w * 4 + j) * 512]),
            16, 0, 0);
    }

    short8 afrag[4][4];
    #pragma unroll
    for (int sm = 0; sm < 4; ++sm)
        #pragma unroll
        for (int kc = 0; kc < 4; ++kc) {
            int row = rowbase + sm * 16 + (l & 15);
            int k0 = kc * 32 + (l >> 4) * 8;
            afrag[sm][kc] = *reinterpret_cast<const short8*>(eb + (size_t)row * Dd + k0);
        }

    float rsq[4][4]; int rlb[4][4];
    #pragma unroll
    for (int sm = 0; sm < 4; ++sm)
        #pragma unroll
        for (int r = 0; r < 4; ++r) {
            int row = rowbase + sm * 16 + (l >> 4) * 4 + r;
            rsq[sm][r] = sqn[row];
            rlb[sm][r] = lab[row];
        }
    int cj[2]; float csq[2]; int clb[2];
    #pragma unroll
    for (int sn = 0; sn < 2; ++sn) {
        cj[sn] = c0 + colb + sn * 16 + (l & 15);
        csq[sn] = sqn[cj[sn]];
        clb[sn] = lab[cj[sn]];
    }

    __syncthreads();

    f32x4 acc[4][2];
    #pragma unroll
    for (int sm = 0; sm < 4; ++sm)
        #pragma unroll
        for (int sn = 0; sn < 2; ++sn)
            acc[sm][sn] = (f32x4){0.f, 0.f, 0.f, 0.f};

    #pragma unroll
    for (int kc = 0; kc < 4; ++kc) {
        short8 bfr[2];
        #pragma unroll
        for (int sn = 0; sn < 2; ++sn) {
            int rcol = colb + sn * 16 + (l & 15);
            int rkb = (kc * 64 + (l >> 4) * 16) ^ ((rcol & 7) << 4);
            bfr[sn] = *reinterpret_cast<const short8*>(swt + rcol * 128 + (rkb >> 1));
        }
        #pragma unroll
        for (int sn = 0; sn < 2; ++sn)
            #pragma unroll
            for (int sm = 0; sm < 4; ++sm)
                acc[sm][sn] = __builtin_amdgcn_mfma_f32_16x16x32_bf16(
                    afrag[sm][kc], bfr[sn], acc[sm][sn], 0, 0, 0);
    }

    float vhp[4][4], vhn[4][4], vct[4][4];
    #pragma unroll
    for (int sm = 0; sm < 4; ++sm)
        #pragma unroll
        for (int r = 0; r < 4; ++r) { vhp[sm][r] = 0.f; vhn[sm][r] = 1e30f; vct[sm][r] = 0.f; }

    #pragma unroll
    for (int sm = 0; sm < 4; ++sm)
        #pragma unroll
        for (int r = 0; r < 4; ++r) {
            int rg = rowbase + sm * 16 + (l >> 4) * 4 + r;
            #pragma unroll
            for (int sn = 0; sn < 2; ++sn) {
                float d2 = fmaf(acc[sm][sn][r], -2.f, rsq[sm][r] + csq[sn]);
                float dist = sqrtf(fmaxf(d2, 0.f) + 1e-16f);
                bool same = (rlb[sm][r] == clb[sn]);
                bool psel = same && (rg != cj[sn]);
                if (psel) { vhp[sm][r] = fmaxf(vhp[sm][r], dist); vct[sm][r] += 1.f; }
                if (!same) vhn[sm][r] = fminf(vhn[sm][r], dist);
            }
        }

    #pragma unroll
    for (int sm = 0; sm < 4; ++sm)
        #pragma unroll
        for (int r = 0; r < 4; ++r) {
            float a = vhp[sm][r], b = vhn[sm][r], c = vct[sm][r];
            #pragma unroll
            for (int o = 1; o < 16; o <<= 1) {
                a = fmaxf(a, __shfl_xor(a, o));
                b = fminf(b, __shfl_xor(b, o));
                c += __shfl_xor(c, o);
            }
            if ((l & 15) == 0) {
                int row = (w & 1) * 64 + sm * 16 + (l >> 4) * 4 + r;
                red[row][w >> 1][0] = a;
                red[row][w >> 1][1] = b;
                red[row][w >> 1][2] = c;
            }
        }
    __syncthreads();
    if (t < 128) {
        float a = fmaxf(red[t][0][0], red[t][1][0]);
        float b = fminf(red[t][0][1], red[t][1][1]);
        float c = red[t][0][2] + red[t][1][2];
        hp[(size_t)split * Bn + r0 + t] = a;
        hn[(size_t)split * Bn + r0 + t] = b;
        cnt[(size_t)split * Bn + r0 + t] = c;
    }
}

// ---------------- per-row merge -> per-block partials (no atomics) ----------------
__launch_bounds__(256)
__global__ void final_k(const float* __restrict__ ps, const float* __restrict__ bx,
                        const float* __restrict__ tg, const float* __restrict__ hp,
                        const float* __restrict__ hn, const float* __restrict__ cnt,
                        float* __restrict__ gpart) {
    __shared__ float sA[4], sT[4], sV[4];
    int row = blockIdx.x * 256 + threadIdx.x;
    float s = 0.f;
    for (int u = 0; u < ASPL; ++u) s += ps[(size_t)u * Bn + row];
    float base = bx[row], targ = tg[row];
    s += __expf(targ - 64.f) - __expf(base - 64.f);
    float lse = 64.f + logf(s);
    float arcs = lse - 0.9f * targ - 0.1f * (targ - base) / (float)Cc;

    float a = 0.f, b = 1e30f, c = 0.f;
    for (int u = 0; u < TS; ++u) {
        a = fmaxf(a, hp[(size_t)u * Bn + row]);
        b = fminf(b, hn[(size_t)u * Bn + row]);
        c += cnt[(size_t)u * Bn + row];
    }
    float tl = fmaxf(a - b + 0.3f, 0.f);
    float tris = (c > 0.f) ? tl : 0.f;
    float vals = (c > 0.f) ? 1.f : 0.f;

    #pragma unroll
    for (int o = 32; o > 0; o >>= 1) {
        arcs += __shfl_xor(arcs, o);
        tris += __shfl_xor(tris, o);
        vals += __shfl_xor(vals, o);
    }
    int wid = threadIdx.x >> 6, lane = threadIdx.x & 63;
    if (lane == 0) { sA[wid] = arcs; sT[wid] = tris; sV[wid] = vals; }
    __syncthreads();
    if (threadIdx.x == 0) {
        gpart[blockIdx.x * 3 + 0] = sA[0] + sA[1] + sA[2] + sA[3];
        gpart[blockIdx.x * 3 + 1] = sT[0] + sT[1] + sT[2] + sT[3];
        gpart[blockIdx.x * 3 + 2] = sV[0] + sV[1] + sV[2] + sV[3];
    }
}

// ---------------- scalar finish ----------------
__global__ void final2_k(const float* __restrict__ gpart, const float* __restrict__ es,
                         const float* __restrict__ wsum, float* __restrict__ out) {
    int l = threadIdx.x;   // 64
    float x = es[l] * wsum[l] + es[l + 64] * wsum[l + 64];
    #pragma unroll
    for (int o = 32; o > 0; o >>= 1) x += __shfl_xor(x, o);
    if (l == 0) {
        float A = 0.f, T = 0.f, V = 0.f;
        for (int b = 0; b < Bn / 256; ++b) {
            A += gpart[b * 3 + 0];
            T += gpart[b * 3 + 1];
            V += gpart[b * 3 + 2];
        }
        float tri = (V > 0.f) ? (T / fmaxf(V, 1.f)) : 0.f;
        out[0] = (A - 6.4f * x / (float)Cc) / (float)Bn + 0.5f * tri;
    }
}

extern "C" void kernel_launch(void* const* d_in, const int* in_sizes, int n_in,
                              void* d_out, int out_size, void* d_ws, size_t ws_size,
                              hipStream_t stream) {
    const float* emb = (const float*)d_in[0];
    const float* W = (const float*)d_in[1];
    const int* lab = (const int*)d_in[2];
    float* out = (float*)d_out;

    unsigned short* embn = (unsigned short*)d_ws;          // 2048*128 bf16
    unsigned short* rawb = embn + (size_t)Bn * Dd;         // 2048*128 bf16
    unsigned short* wnb = rawb + (size_t)Bn * Dd;          // 50000*128 bf16
    float* sqn = (float*)(wnb + (size_t)Cc * Dd);          // 2048
    float* ps = sqn + Bn;                                  // ASPL*2048
    float* bx = ps + (size_t)ASPL * Bn;                    // 2048
    float* tg = bx + Bn;                                   // 2048
    float* hp = tg + Bn;                                   // TS*2048
    float* hn = hp + (size_t)TS * Bn;                      // TS*2048
    float* ct = hn + (size_t)TS * Bn;                      // TS*2048
    float* esum = ct + (size_t)TS * Bn;                    // 128
    float* wsum = esum + 128;                              // 128
    float* gpart = wsum + 128;                             // 24

    norm_all<<<256 + Cc / 8, 256, 0, stream>>>(emb, W, embn, rawb, sqn, wnb, esum);
    aux_k<<<272 + Bn / 4, 256, 0, stream>>>(embn, wnb, lab, esum, wsum, bx, tg);
    arc_main<<<512, 256, 0, stream>>>(embn, wnb, ps);
    trip_k<<<dim3(16, TS), 256, 0, stream>>>(rawb, sqn, lab, hp, hn, ct);
    final_k<<<Bn / 256, 256, 0, stream>>>(ps, bx, tg, hp, hn, ct, gpart);
    final2_k<<<1, 64, 0, stream>>>(gpart, esum, wsum, out);
}